// Round 1
// baseline (546.743 us; speedup 1.0000x reference)
//
#include <hip/hip_runtime.h>

#define NB 8192
#define VV 100000
#define DD 64
#define ND 15
#define SL 50
#define FF 16
#define HH 30
#define PN 120

// pair p -> (r<<4)|c for all combinations(16,2) in lexicographic order
__constant__ unsigned char pair_rc[PN] = {
    1,2,3,4,5,6,7,8,9,10,11,12,13,14,15,
    18,19,20,21,22,23,24,25,26,27,28,29,30,31,
    35,36,37,38,39,40,41,42,43,44,45,46,47,
    52,53,54,55,56,57,58,59,60,61,62,63,
    69,70,71,72,73,74,75,76,77,78,79,
    86,87,88,89,90,91,92,93,94,95,
    103,104,105,106,107,108,109,110,111,
    120,121,122,123,124,125,126,127,
    137,138,139,140,141,142,143,
    154,155,156,157,158,159,
    171,172,173,174,175,
    188,189,190,191,
    205,206,207,
    222,223,
    239
};

__global__ __launch_bounds__(256) void pnn_fused(
    const int* __restrict__ dense_ids, const int* __restrict__ seq_ids,
    const float* __restrict__ tables_dense, const float* __restrict__ table_seq,
    const float* __restrict__ inner_w, const float* __restrict__ W1,
    const float* __restrict__ b1, const float* __restrict__ W2,
    const float* __restrict__ b2, float* __restrict__ out)
{
    // X[wave] = [ emb flat (1024) | lp (120) ]  (stride 1152 for alignment)
    __shared__ float X[4][1152];

    const int wave = threadIdx.x >> 6;
    const int lane = threadIdx.x & 63;
    const int s = (blockIdx.x << 2) | wave;   // sample index, exact grid

    // ---------------- Phase A: gathers (lane = dim d) ----------------
    {
        const int d = lane;
        float e[FF];
        const int* dp = dense_ids + s * ND;
        #pragma unroll
        for (int f = 0; f < ND; ++f) {
            int id = dp[f];
            e[f] = tables_dense[((size_t)f * VV + id) * DD + d];
        }
        float a0 = 0.0f, a1 = 0.0f;
        const int* sp = seq_ids + s * SL;
        #pragma unroll 5
        for (int i = 0; i < SL; i += 2) {
            int id0 = sp[i];
            int id1 = sp[i + 1];
            a0 += table_seq[(size_t)id0 * DD + d];
            a1 += table_seq[(size_t)id1 * DD + d];
        }
        e[15] = (a0 + a1) * (1.0f / SL);
        #pragma unroll
        for (int f = 0; f < FF; ++f) X[wave][f * DD + d] = e[f];
    }
    __syncthreads();

    // ---------------- Phase B: 120 pair inner products ----------------
    #pragma unroll
    for (int pp = 0; pp < 2; ++pp) {
        int p = lane + pp * 64;
        if (p < PN) {
            int rc = pair_rc[p];
            const float* er = &X[wave][(rc >> 4) * DD];
            const float* ec = &X[wave][(rc & 15) * DD];
            const float* w  = inner_w + p * DD;
            float acc = 0.0f;
            #pragma unroll 4
            for (int i = 0; i < DD; ++i) {
                int d = (i + lane) & (DD - 1);   // stagger: rotate LDS banks
                acc = fmaf(er[d] * ec[d], w[d], acc);
            }
            X[wave][FF * DD + p] = acc;
        }
    }
    __syncthreads();

    // ---------------- Phase C: h = relu(X@W1+b1); out = sigmoid(h@W2+b2) ----
    const int j = lane & 31;
    const int half = lane >> 5;          // two half-waves split the K dim
    float acc = 0.0f;
    if (j < HH) {
        const int kbase = half * 572;
        const float* xp = &X[wave][kbase];
        const float* w1 = W1 + j;
        #pragma unroll 4
        for (int k = 0; k < 572; ++k)
            acc = fmaf(xp[k], w1[(size_t)(kbase + k) * HH], acc);
    }
    acc += __shfl_xor(acc, 32);          // combine K-halves into lanes 0..31

    float t = 0.0f;
    if (lane < HH) t = fmaxf(acc + b1[lane], 0.0f) * W2[lane];
    #pragma unroll
    for (int off = 16; off > 0; off >>= 1) t += __shfl_xor(t, off);

    if (lane == 0) {
        float z = t + b2[0];
        out[s] = 1.0f / (1.0f + __expf(-z));
    }
}

extern "C" void kernel_launch(void* const* d_in, const int* in_sizes, int n_in,
                              void* d_out, int out_size, void* d_ws, size_t ws_size,
                              hipStream_t stream) {
    const int* dense_ids    = (const int*)d_in[0];
    const int* seq_ids      = (const int*)d_in[1];
    const float* tables_dense = (const float*)d_in[2];
    const float* table_seq    = (const float*)d_in[3];
    const float* inner_w      = (const float*)d_in[4];
    const float* W1           = (const float*)d_in[5];
    const float* b1           = (const float*)d_in[6];
    const float* W2           = (const float*)d_in[7];
    const float* b2           = (const float*)d_in[8];

    pnn_fused<<<NB / 4, 256, 0, stream>>>(
        dense_ids, seq_ids, tables_dense, table_seq,
        inner_w, W1, b1, W2, b2, (float*)d_out);
}

// Round 2
// 473.206 us; speedup vs baseline: 1.1554x; 1.1554x over previous
//
#include <hip/hip_runtime.h>

#define VV 100000
#define DD 64
#define ND 15
#define SL 50
#define HH 30
#define PN 120
#define KX 1152            // padded K: 1024 emb + 120 lp + 8 zero
#define SPB 16             // samples per block
#define XROWB 2320         // bytes per sample row in LDS (1160 bf16, pad keeps b128 banks spread)

typedef __attribute__((ext_vector_type(8))) short short8;
typedef __attribute__((ext_vector_type(4))) float f32x4;

// pair p -> (r<<4)|c, 120 pairs + 8 zero pads
__constant__ unsigned char pair_rc[128] = {
    1,2,3,4,5,6,7,8,9,10,11,12,13,14,15,
    18,19,20,21,22,23,24,25,26,27,28,29,30,31,
    35,36,37,38,39,40,41,42,43,44,45,46,47,
    52,53,54,55,56,57,58,59,60,61,62,63,
    69,70,71,72,73,74,75,76,77,78,79,
    86,87,88,89,90,91,92,93,94,95,
    103,104,105,106,107,108,109,110,111,
    120,121,122,123,124,125,126,127,
    137,138,139,140,141,142,143,
    154,155,156,157,158,159,
    171,172,173,174,175,
    188,189,190,191,
    205,206,207,
    222,223,
    239,
    0,0,0,0,0,0,0,0
};

__device__ __forceinline__ unsigned short f2bf(float x) {
    unsigned u = __float_as_uint(x);
    u += 0x7fffu + ((u >> 16) & 1u);          // RNE
    return (unsigned short)(u >> 16);
}
__device__ __forceinline__ float bflo(unsigned u) { return __uint_as_float(u << 16); }
__device__ __forceinline__ float bfhi(unsigned u) { return __uint_as_float(u & 0xffff0000u); }

// ---- prep: W1 (1144x30 f32) -> W1t (32x1152 bf16, transposed, zero-padded) in d_ws ----
__global__ __launch_bounds__(256) void prep_w1t(const float* __restrict__ W1,
                                                unsigned* __restrict__ w1t) {
    int u = blockIdx.x * 256 + threadIdx.x;    // 0..18431 (uint words, 2 bf16 each)
    int n = u / 576;                           // output row (j), 0..31
    int k2 = u - n * 576;
    int k = k2 * 2;
    float v0 = (n < HH && k < 1144) ? W1[(size_t)k * HH + n] : 0.f;
    float v1 = (n < HH && (k + 1) < 1144) ? W1[(size_t)(k + 1) * HH + n] : 0.f;
    w1t[u] = (unsigned)f2bf(v0) | ((unsigned)f2bf(v1) << 16);
}

__global__ __launch_bounds__(256) void pnn_main(
    const int* __restrict__ dense_ids, const int* __restrict__ seq_ids,
    const float* __restrict__ tables_dense, const float* __restrict__ table_seq,
    const float* __restrict__ inner_w, const unsigned short* __restrict__ w1t,
    const float* __restrict__ b1, const float* __restrict__ W2,
    const float* __restrict__ b2, float* __restrict__ out)
{
    // X: bf16 [16 samples][1160] with 16B-chunk XOR swizzle per 64-elt row
    __shared__ __align__(16) unsigned char Xraw[SPB * XROWB];
    __shared__ int ids_d[SPB * ND];
    __shared__ int ids_s[SPB * SL];
    __shared__ float red[4 * SPB * 32];

    const int t = threadIdx.x;
    const int wave = t >> 6;
    const int lane = t & 63;
    const int sbase = blockIdx.x * SPB;

    // ---- stage ids ----
    if (t < SPB * ND) ids_d[t] = dense_ids[sbase * ND + t];
    for (int i = t; i < SPB * SL; i += 256) ids_s[i] = seq_ids[sbase * SL + i];
    __syncthreads();

    // ---- phase A: gathers, lane = d-pair, two f-rows per instr ----
    {
        const int half = lane >> 5;
        const int dl = (lane & 31) * 2;
        for (int si = 0; si < 4; ++si) {
            const int sl_ = wave * 4 + si;
            #pragma unroll
            for (int i = 0; i < 8; ++i) {
                int f = 2 * i + half;
                if (f < ND) {
                    int id = ids_d[sl_ * ND + f];
                    float2 v = *(const float2*)(tables_dense + ((size_t)f * VV + id) * DD + dl);
                    unsigned pk = (unsigned)f2bf(v.x) | ((unsigned)f2bf(v.y) << 16);
                    int k = f * DD + dl;
                    int ch = (k >> 3) ^ (f & 7);
                    *(unsigned*)(&Xraw[sl_ * XROWB + ch * 16 + (dl & 7) * 2]) = pk;
                }
            }
            float a0 = 0.f, a1 = 0.f;
            const int* sid = &ids_s[sl_ * SL];
            #pragma unroll 5
            for (int i = 0; i < 25; ++i) {
                int id = sid[2 * i + half];
                float2 v = *(const float2*)(table_seq + (size_t)id * DD + dl);
                a0 += v.x; a1 += v.y;
            }
            a0 += __shfl_xor(a0, 32);
            a1 += __shfl_xor(a1, 32);
            if (half == 0) {
                unsigned pk = (unsigned)f2bf(a0 * 0.02f) | ((unsigned)f2bf(a1 * 0.02f) << 16);
                int k = 15 * DD + dl;
                int ch = (k >> 3) ^ 7;
                *(unsigned*)(&Xraw[sl_ * XROWB + ch * 16 + (dl & 7) * 2]) = pk;
            }
        }
    }
    __syncthreads();

    // ---- phase B: 120 pair dots; thread=pair, w row in regs, reused over 8 samples ----
    {
        const int p = t & 127;
        const int sg = t >> 7;
        const bool valid = p < PN;
        const int rc = pair_rc[p];
        const int r = rc >> 4, c = rc & 15;
        f32x4 w4[16];
        if (valid) {
            const float* wp = inner_w + p * DD;
            #pragma unroll
            for (int i = 0; i < 16; ++i) w4[i] = *(const f32x4*)(wp + i * 4);
        }
        #pragma unroll 2
        for (int si = 0; si < 8; ++si) {
            const int sl_ = sg * 8 + si;
            float acc = 0.f;
            if (valid) {
                #pragma unroll
                for (int ch = 0; ch < 8; ++ch) {
                    int cr = (r * 8 + ch) ^ (r & 7);
                    int cc = (c * 8 + ch) ^ (c & 7);
                    uint4 xr = *(const uint4*)(&Xraw[sl_ * XROWB + cr * 16]);
                    uint4 xc = *(const uint4*)(&Xraw[sl_ * XROWB + cc * 16]);
                    acc = fmaf(bflo(xr.x) * bflo(xc.x), w4[ch * 2].x, acc);
                    acc = fmaf(bfhi(xr.x) * bfhi(xc.x), w4[ch * 2].y, acc);
                    acc = fmaf(bflo(xr.y) * bflo(xc.y), w4[ch * 2].z, acc);
                    acc = fmaf(bfhi(xr.y) * bfhi(xc.y), w4[ch * 2].w, acc);
                    acc = fmaf(bflo(xr.z) * bflo(xc.z), w4[ch * 2 + 1].x, acc);
                    acc = fmaf(bfhi(xr.z) * bfhi(xc.z), w4[ch * 2 + 1].y, acc);
                    acc = fmaf(bflo(xr.w) * bflo(xc.w), w4[ch * 2 + 1].z, acc);
                    acc = fmaf(bfhi(xr.w) * bfhi(xc.w), w4[ch * 2 + 1].w, acc);
                }
            }
            int k = 1024 + p;                       // lp (+ zero pad p>=120)
            int ch = (k >> 3) ^ ((k >> 6) & 7);
            *(unsigned short*)(&Xraw[sl_ * XROWB + ch * 16 + (p & 7) * 2]) = f2bf(acc);
        }
    }
    __syncthreads();

    // ---- phase C: out[16x30] = X[16x1152] @ W1t^T via MFMA 16x16x32, K split over 4 waves ----
    {
        const int m = lane & 15;                    // A row (sample) / B col (j) / D col
        const int kg = lane >> 4;
        f32x4 acc0 = {0.f, 0.f, 0.f, 0.f}, acc1 = {0.f, 0.f, 0.f, 0.f};
        #pragma unroll
        for (int i = 0; i < 9; ++i) {
            int kt = wave * 9 + i;
            int k = kt * 32 + kg * 8;
            int ch = (kt * 4 + kg) ^ ((kt >> 1) & 7);
            short8 a  = *(const short8*)(&Xraw[m * XROWB + ch * 16]);
            short8 b0 = *(const short8*)(w1t + (size_t)m * KX + k);
            short8 b1 = *(const short8*)(w1t + (size_t)(m + 16) * KX + k);
            acc0 = __builtin_amdgcn_mfma_f32_16x16x32_bf16(a, b0, acc0, 0, 0, 0);
            acc1 = __builtin_amdgcn_mfma_f32_16x16x32_bf16(a, b1, acc1, 0, 0, 0);
        }
        #pragma unroll
        for (int reg = 0; reg < 4; ++reg) {
            int smp = kg * 4 + reg;                 // D row = (lane>>4)*4+reg (m89-verified)
            red[wave * 512 + smp * 32 + m] = acc0[reg];
            red[wave * 512 + smp * 32 + 16 + m] = acc1[reg];
        }
    }
    __syncthreads();

    // ---- final: sum K-partials, bias, relu, dot W2, sigmoid ----
    {
        float w2v = (lane < HH) ? W2[lane] : 0.f;
        float b1v = (lane < HH) ? b1[lane] : 0.f;
        for (int si = 0; si < 4; ++si) {
            int sl_ = wave * 4 + si;
            float v = 0.f;
            if (lane < HH) {
                v = red[0 * 512 + sl_ * 32 + lane] + red[1 * 512 + sl_ * 32 + lane]
                  + red[2 * 512 + sl_ * 32 + lane] + red[3 * 512 + sl_ * 32 + lane];
                v = fmaxf(v + b1v, 0.f) * w2v;
            }
            #pragma unroll
            for (int off = 32; off > 0; off >>= 1) v += __shfl_xor(v, off);
            if (lane == 0) {
                float z = v + b2[0];
                out[sbase + sl_] = 1.f / (1.f + __expf(-z));
            }
        }
    }
}

extern "C" void kernel_launch(void* const* d_in, const int* in_sizes, int n_in,
                              void* d_out, int out_size, void* d_ws, size_t ws_size,
                              hipStream_t stream) {
    const int* dense_ids      = (const int*)d_in[0];
    const int* seq_ids        = (const int*)d_in[1];
    const float* tables_dense = (const float*)d_in[2];
    const float* table_seq    = (const float*)d_in[3];
    const float* inner_w      = (const float*)d_in[4];
    const float* W1           = (const float*)d_in[5];
    const float* b1           = (const float*)d_in[6];
    const float* W2           = (const float*)d_in[7];
    const float* b2           = (const float*)d_in[8];

    // W1t: 32 x 1152 bf16 = 73728 elts = 18432 uints -> 72 blocks
    prep_w1t<<<72, 256, 0, stream>>>(W1, (unsigned*)d_ws);
    pnn_main<<<512, 256, 0, stream>>>(dense_ids, seq_ids, tables_dense, table_seq,
                                      inner_w, (const unsigned short*)d_ws,
                                      b1, W2, b2, (float*)d_out);
}

// Round 3
// 471.354 us; speedup vs baseline: 1.1599x; 1.0039x over previous
//
#include <hip/hip_runtime.h>

#define VV 100000
#define DD 64
#define ND 15
#define SL 50
#define HH 30
#define PN 120
#define KX 1152            // padded K: 1024 emb + 120 lp + 8 zero
#define SPB 8              // samples per block
#define XROWB 2320         // bytes per sample row in LDS (1160 bf16, pad spreads b128 banks)

typedef __attribute__((ext_vector_type(8))) short short8;
typedef __attribute__((ext_vector_type(4))) float f32x4;
typedef __attribute__((ext_vector_type(2))) float f32x2;

// pair p -> (r<<4)|c, 120 pairs + 8 zero pads
__constant__ unsigned char pair_rc[128] = {
    1,2,3,4,5,6,7,8,9,10,11,12,13,14,15,
    18,19,20,21,22,23,24,25,26,27,28,29,30,31,
    35,36,37,38,39,40,41,42,43,44,45,46,47,
    52,53,54,55,56,57,58,59,60,61,62,63,
    69,70,71,72,73,74,75,76,77,78,79,
    86,87,88,89,90,91,92,93,94,95,
    103,104,105,106,107,108,109,110,111,
    120,121,122,123,124,125,126,127,
    137,138,139,140,141,142,143,
    154,155,156,157,158,159,
    171,172,173,174,175,
    188,189,190,191,
    205,206,207,
    222,223,
    239,
    0,0,0,0,0,0,0,0
};

__device__ __forceinline__ unsigned short f2bf(float x) {
    unsigned u = __float_as_uint(x);
    u += 0x7fffu + ((u >> 16) & 1u);          // RNE
    return (unsigned short)(u >> 16);
}
__device__ __forceinline__ float bflo(unsigned u) { return __uint_as_float(u << 16); }
__device__ __forceinline__ float bfhi(unsigned u) { return __uint_as_float(u & 0xffff0000u); }

// ---- prep: W1 (1144x30 f32) -> W1t (32x1152 bf16, transposed, zero-padded) in d_ws ----
__global__ __launch_bounds__(256) void prep_w1t(const float* __restrict__ W1,
                                                unsigned* __restrict__ w1t) {
    int u = blockIdx.x * 256 + threadIdx.x;    // 0..18431 (uint words, 2 bf16 each)
    int n = u / 576;                           // output row (j), 0..31
    int k2 = u - n * 576;
    int k = k2 * 2;
    float v0 = (n < HH && k < 1144) ? W1[(size_t)k * HH + n] : 0.f;
    float v1 = (n < HH && (k + 1) < 1144) ? W1[(size_t)(k + 1) * HH + n] : 0.f;
    w1t[u] = (unsigned)f2bf(v0) | ((unsigned)f2bf(v1) << 16);
}

__global__ __launch_bounds__(256) void pnn_main(
    const int* __restrict__ dense_ids, const int* __restrict__ seq_ids,
    const float* __restrict__ tables_dense, const float* __restrict__ table_seq,
    const float* __restrict__ inner_w, const unsigned short* __restrict__ w1t,
    const float* __restrict__ b1, const float* __restrict__ W2,
    const float* __restrict__ b2, float* __restrict__ out)
{
    // X: bf16 [8 samples][1160] with 16B-chunk XOR swizzle per 64-elt row
    __shared__ __align__(16) unsigned char Xraw[SPB * XROWB];
    __shared__ int ids_d[SPB * ND];
    __shared__ int ids_s[SPB * SL];
    __shared__ float red[4 * SPB * 32];

    const int t = threadIdx.x;
    const int wave = t >> 6;
    const int lane = t & 63;
    const int sbase = blockIdx.x * SPB;

    // ---- stage ids ----
    if (t < SPB * ND) ids_d[t] = dense_ids[sbase * ND + t];
    for (int i = t; i < SPB * SL; i += 256) ids_s[i] = seq_ids[sbase * SL + i];
    __syncthreads();

    // ---- phase A: gathers, lane = d-pair; 2 samples per wave, fully unrolled ----
    {
        const int half = lane >> 5;
        const int dl = (lane & 31) * 2;
        #pragma unroll
        for (int si = 0; si < 2; ++si) {
            const int sl_ = wave * 2 + si;
            #pragma unroll
            for (int i = 0; i < 8; ++i) {
                int f = 2 * i + half;
                if (f < ND) {
                    int id = ids_d[sl_ * ND + f];
                    // nontemporal: dense rows are touched once; keep seq table in L3
                    f32x2 v = __builtin_nontemporal_load(
                        (const f32x2*)(tables_dense + ((size_t)f * VV + id) * DD + dl));
                    unsigned pk = (unsigned)f2bf(v.x) | ((unsigned)f2bf(v.y) << 16);
                    int k = f * DD + dl;
                    int ch = (k >> 3) ^ (f & 7);
                    *(unsigned*)(&Xraw[sl_ * XROWB + ch * 16 + (dl & 7) * 2]) = pk;
                }
            }
            float a0 = 0.f, a1 = 0.f;
            const int* sid = &ids_s[sl_ * SL];
            #pragma unroll 5
            for (int i = 0; i < 25; ++i) {
                int id = sid[2 * i + half];
                f32x2 v = *(const f32x2*)(table_seq + (size_t)id * DD + dl);
                a0 += v.x; a1 += v.y;
            }
            a0 += __shfl_xor(a0, 32);
            a1 += __shfl_xor(a1, 32);
            if (half == 0) {
                unsigned pk = (unsigned)f2bf(a0 * 0.02f) | ((unsigned)f2bf(a1 * 0.02f) << 16);
                int k = 15 * DD + dl;
                int ch = (k >> 3) ^ 7;
                *(unsigned*)(&Xraw[sl_ * XROWB + ch * 16 + (dl & 7) * 2]) = pk;
            }
        }
    }
    __syncthreads();

    // ---- phase B: 120 pair dots; thread=pair, w row in regs, reused over 4 samples ----
    {
        const int p = t & 127;
        const int sg = t >> 7;
        const bool valid = p < PN;
        const int rc = pair_rc[p];
        const int r = rc >> 4, c = rc & 15;
        f32x4 w4[16];
        if (valid) {
            const float* wp = inner_w + p * DD;
            #pragma unroll
            for (int i = 0; i < 16; ++i) w4[i] = *(const f32x4*)(wp + i * 4);
        }
        #pragma unroll 2
        for (int si = 0; si < 4; ++si) {
            const int sl_ = sg * 4 + si;
            float acc = 0.f;
            if (valid) {
                #pragma unroll
                for (int ch = 0; ch < 8; ++ch) {
                    int cr = (r * 8 + ch) ^ (r & 7);
                    int cc = (c * 8 + ch) ^ (c & 7);
                    uint4 xr = *(const uint4*)(&Xraw[sl_ * XROWB + cr * 16]);
                    uint4 xc = *(const uint4*)(&Xraw[sl_ * XROWB + cc * 16]);
                    acc = fmaf(bflo(xr.x) * bflo(xc.x), w4[ch * 2].x, acc);
                    acc = fmaf(bfhi(xr.x) * bfhi(xc.x), w4[ch * 2].y, acc);
                    acc = fmaf(bflo(xr.y) * bflo(xc.y), w4[ch * 2].z, acc);
                    acc = fmaf(bfhi(xr.y) * bfhi(xc.y), w4[ch * 2].w, acc);
                    acc = fmaf(bflo(xr.z) * bflo(xc.z), w4[ch * 2 + 1].x, acc);
                    acc = fmaf(bfhi(xr.z) * bfhi(xc.z), w4[ch * 2 + 1].y, acc);
                    acc = fmaf(bflo(xr.w) * bflo(xc.w), w4[ch * 2 + 1].z, acc);
                    acc = fmaf(bfhi(xr.w) * bfhi(xc.w), w4[ch * 2 + 1].w, acc);
                }
            }
            int k = 1024 + p;                       // lp (+ zero pad p>=120)
            int ch = (k >> 3) ^ ((k >> 6) & 7);
            *(unsigned short*)(&Xraw[sl_ * XROWB + ch * 16 + (p & 7) * 2]) = f2bf(acc);
        }
    }
    __syncthreads();

    // ---- phase C: out[8x30] = X[8x1152] @ W1t^T via MFMA 16x16x32, K split over 4 waves ----
    {
        const int m = lane & 15;                    // A row (sample, mod 8) / B col (j)
        const int kg = lane >> 4;
        f32x4 acc0 = {0.f, 0.f, 0.f, 0.f}, acc1 = {0.f, 0.f, 0.f, 0.f};
        #pragma unroll
        for (int i = 0; i < 9; ++i) {
            int kt = wave * 9 + i;
            int k = kt * 32 + kg * 8;
            int ch = (kt * 4 + kg) ^ ((kt >> 1) & 7);
            short8 a  = *(const short8*)(&Xraw[(m & 7) * XROWB + ch * 16]);
            short8 b0 = *(const short8*)(w1t + (size_t)m * KX + k);
            short8 b1 = *(const short8*)(w1t + (size_t)(m + 16) * KX + k);
            acc0 = __builtin_amdgcn_mfma_f32_16x16x32_bf16(a, b0, acc0, 0, 0, 0);
            acc1 = __builtin_amdgcn_mfma_f32_16x16x32_bf16(a, b1, acc1, 0, 0, 0);
        }
        if (kg < 2) {                               // D rows 0..7 are the real samples
            #pragma unroll
            for (int reg = 0; reg < 4; ++reg) {
                int smp = kg * 4 + reg;             // D row = (lane>>4)*4+reg (m89-verified)
                red[wave * (SPB * 32) + smp * 32 + m] = acc0[reg];
                red[wave * (SPB * 32) + smp * 32 + 16 + m] = acc1[reg];
            }
        }
    }
    __syncthreads();

    // ---- final: sum K-partials, bias, relu, dot W2, sigmoid ----
    {
        float w2v = (lane < HH) ? W2[lane] : 0.f;
        float b1v = (lane < HH) ? b1[lane] : 0.f;
        #pragma unroll
        for (int si = 0; si < 2; ++si) {
            int sl_ = wave * 2 + si;
            float v = 0.f;
            if (lane < HH) {
                v = red[0 * (SPB * 32) + sl_ * 32 + lane] + red[1 * (SPB * 32) + sl_ * 32 + lane]
                  + red[2 * (SPB * 32) + sl_ * 32 + lane] + red[3 * (SPB * 32) + sl_ * 32 + lane];
                v = fmaxf(v + b1v, 0.f) * w2v;
            }
            #pragma unroll
            for (int off = 32; off > 0; off >>= 1) v += __shfl_xor(v, off);
            if (lane == 0) {
                float z = v + b2[0];
                out[sbase + sl_] = 1.f / (1.f + __expf(-z));
            }
        }
    }
}

extern "C" void kernel_launch(void* const* d_in, const int* in_sizes, int n_in,
                              void* d_out, int out_size, void* d_ws, size_t ws_size,
                              hipStream_t stream) {
    const int* dense_ids      = (const int*)d_in[0];
    const int* seq_ids        = (const int*)d_in[1];
    const float* tables_dense = (const float*)d_in[2];
    const float* table_seq    = (const float*)d_in[3];
    const float* inner_w      = (const float*)d_in[4];
    const float* W1           = (const float*)d_in[5];
    const float* b1           = (const float*)d_in[6];
    const float* W2           = (const float*)d_in[7];
    const float* b2           = (const float*)d_in[8];

    // W1t: 32 x 1152 bf16 = 73728 elts = 18432 uints -> 72 blocks
    prep_w1t<<<72, 256, 0, stream>>>(W1, (unsigned*)d_ws);
    pnn_main<<<1024, 256, 0, stream>>>(dense_ids, seq_ids, tables_dense, table_seq,
                                       inner_w, (const unsigned short*)d_ws,
                                       b1, W2, b2, (float*)d_out);
}